// Round 2
// baseline (1317.491 us; speedup 1.0000x reference)
//
#include <hip/hip_runtime.h>

// Window attention, fused single kernel per window.
// B_=8192 windows, N=64, C=192, H=6, hd=32, nW=4096.

typedef __bf16 bf16x8 __attribute__((ext_vector_type(8)));
typedef float f32x4 __attribute__((ext_vector_type(4)));
typedef unsigned short u16x8 __attribute__((ext_vector_type(8)));

__device__ inline unsigned short f2bf(float f) {
    union { float f; unsigned u; } v; v.f = f;
    unsigned r = v.u + 0x7fffu + ((v.u >> 16) & 1u);
    return (unsigned short)(r >> 16);
}

__device__ inline bf16x8 ld_frag(const unsigned short* p) {
    return __builtin_bit_cast(bf16x8, *(const int4*)p);
}

// ---------------- weight preprocessing: fp32 -> bf16 fragment-linear ----------------
// wsQ: [kt 0..5][nt 0..35][lane 0..63][jj 0..7]  (qkv_w is (192,576) row-major, B[k][n])
// wsP: [kt 0..5][nt 0..11][lane 0..63][jj 0..7]  (proj_w is (192,192))
__global__ void prep_weights(const float* __restrict__ qkv_w,
                             const float* __restrict__ proj_w,
                             unsigned short* __restrict__ wsQ,
                             unsigned short* __restrict__ wsP) {
    int tid = blockIdx.x * 256 + threadIdx.x;
    if (tid < 110592) {
        int jj = tid & 7, lane = (tid >> 3) & 63;
        int nt = (tid >> 9) % 36, kt = tid / 18432;
        int k = kt * 32 + ((lane >> 4) * 8) + jj;
        int n = nt * 16 + (lane & 15);
        wsQ[tid] = f2bf(qkv_w[k * 576 + n]);
    } else if (tid < 110592 + 36864) {
        int t2 = tid - 110592;
        int jj = t2 & 7, lane = (t2 >> 3) & 63;
        int nt = (t2 >> 9) % 12, kt = (t2 >> 9) / 12;
        int k = kt * 32 + ((lane >> 4) * 8) + jj;
        int n = nt * 16 + (lane & 15);
        wsP[t2] = f2bf(proj_w[k * 192 + n]);
    }
}

// ---------------- main fused kernel: one 6-wave block per window ----------------
__launch_bounds__(384, 3)
__global__ void win_attn(const float* __restrict__ hidden,
                         const float* __restrict__ mask,
                         const float* __restrict__ qkv_b,
                         const float* __restrict__ proj_b,
                         const float* __restrict__ bias_table,
                         const unsigned short* __restrict__ wsQ,
                         const unsigned short* __restrict__ wsP,
                         float* __restrict__ out) {
    // LDS: R0 (24576B) X-frags -> qA -> pA[h<3] ; R1 (24576B) kB -> pA[h>=3] ; R2 (24576B) vB -> xO
    __shared__ char smem[73728];
    unsigned short* R0 = (unsigned short*)smem;
    unsigned short* R1 = (unsigned short*)(smem + 24576);
    unsigned short* R2 = (unsigned short*)(smem + 49152);

    const int b = blockIdx.x;
    const int t = threadIdx.x;
    const int w = t >> 6;    // wave id 0..5 (= head in attention phases)
    const int l = t & 63;    // lane
    const f32x4 z = {0.f, 0.f, 0.f, 0.f};

    // ---- Phase 1: hidden (64x192 f32) -> bf16 A-frags X[kt][mt][lane][8] in R0
    const float* hb = hidden + (size_t)b * 12288;
#pragma unroll
    for (int it = 0; it < 4; ++it) {
        int slot = it * 384 + t;          // 0..1535
        int m  = slot / 24;               // token row 0..63
        int k8 = (slot % 24) * 8;         // col start (multiple of 8)
        float4 f0 = *(const float4*)(hb + m * 192 + k8);
        float4 f1 = *(const float4*)(hb + m * 192 + k8 + 4);
        u16x8 tmp;
        tmp[0] = f2bf(f0.x); tmp[1] = f2bf(f0.y); tmp[2] = f2bf(f0.z); tmp[3] = f2bf(f0.w);
        tmp[4] = f2bf(f1.x); tmp[5] = f2bf(f1.y); tmp[6] = f2bf(f1.z); tmp[7] = f2bf(f1.w);
        int kt = k8 >> 5, mt = m >> 4;
        int lane_ = (m & 15) + 16 * ((k8 >> 3) & 3);
        *(int4*)(R0 + ((kt * 4 + mt) * 64 + lane_) * 8) = __builtin_bit_cast(int4, tmp);
    }
    __syncthreads();

    // ---- Phase 2: QKV GEMM. wave w owns n-tiles 6w..6w+5 (cols 96w..96w+95)
    f32x4 acc[6][4];
#pragma unroll
    for (int i = 0; i < 6; ++i)
#pragma unroll
        for (int mt = 0; mt < 4; ++mt) acc[i][mt] = z;

#pragma unroll
    for (int kt = 0; kt < 6; ++kt) {
        bf16x8 a[4], bf[6];
#pragma unroll
        for (int mt = 0; mt < 4; ++mt)
            a[mt] = ld_frag(R0 + ((kt * 4 + mt) * 64 + l) * 8);
#pragma unroll
        for (int i = 0; i < 6; ++i) {
            int nt = 6 * w + i;
            bf[i] = ld_frag(wsQ + ((kt * 36 + nt) * 64 + l) * 8);
        }
#pragma unroll
        for (int i = 0; i < 6; ++i)
#pragma unroll
            for (int mt = 0; mt < 4; ++mt)
                acc[i][mt] = __builtin_amdgcn_mfma_f32_16x16x32_bf16(a[mt], bf[i], acc[i][mt], 0, 0, 0);
    }
    __syncthreads();   // X dead

    // ---- Phase 3: +bias, scatter q(*scale)/k/v into fragment-linear LDS
    {
        const int qkv_i = w >> 1;
        const float scale = 0.17677669529663687f;  // 32^-0.5
#pragma unroll
        for (int i = 0; i < 6; ++i) {
            int col = 16 * (6 * w + i) + (l & 15);
            float bias = qkv_b[col];
            int h = (col % 192) / 32;
            int d = col & 31;
#pragma unroll
            for (int mt = 0; mt < 4; ++mt) {
#pragma unroll
                for (int j = 0; j < 4; ++j) {
                    int r = 16 * mt + (l >> 4) * 4 + j;
                    float v = acc[i][mt][j] + bias;
                    if (qkv_i == 0) {
                        v *= scale;
                        R0[((h * 4 + mt) * 64 + ((r & 15) + 16 * (d >> 3))) * 8 + (d & 7)] = f2bf(v);
                    } else if (qkv_i == 1) {
                        R1[((h * 4 + mt) * 64 + ((r & 15) + 16 * (d >> 3))) * 8 + (d & 7)] = f2bf(v);
                    } else {
                        R2[(((h * 2 + (r >> 5)) * 2 + (d >> 4)) * 64 + ((d & 15) + 16 * ((r >> 3) & 3))) * 8 + (r & 7)] = f2bf(v);
                    }
                }
            }
        }
    }
    __syncthreads();

    // ---- Phase 4: S = q k^T for head h=w, + rel-pos-bias + mask, softmax
    const int h = w;
    f32x4 s[4][4];
    {
        bf16x8 qf[4], kf[4];
#pragma unroll
        for (int mt = 0; mt < 4; ++mt) qf[mt] = ld_frag(R0 + ((h * 4 + mt) * 64 + l) * 8);
#pragma unroll
        for (int nt = 0; nt < 4; ++nt) kf[nt] = ld_frag(R1 + ((h * 4 + nt) * 64 + l) * 8);
#pragma unroll
        for (int mt = 0; mt < 4; ++mt)
#pragma unroll
            for (int nt = 0; nt < 4; ++nt)
                s[mt][nt] = __builtin_amdgcn_mfma_f32_16x16x32_bf16(qf[mt], kf[nt], z, 0, 0, 0);
    }

    {
        const float* mrow = mask + (size_t)(b & 4095) * 4096;
        int cb = l & 15;
#pragma unroll
        for (int mt = 0; mt < 4; ++mt) {
#pragma unroll
            for (int nt = 0; nt < 4; ++nt) {
#pragma unroll
                for (int j = 0; j < 4; ++j) {
                    int r = 16 * mt + (l >> 4) * 4 + j;
                    int c = 16 * nt + cb;
                    int idx = ((r >> 3) - (c >> 3) + 7) * 15 + (r & 7) - (c & 7) + 7;
                    s[mt][nt][j] += bias_table[idx * 6 + h] + mrow[r * 64 + c];
                }
            }
        }
        // softmax over rows (row lives in a 16-lane group)
#pragma unroll
        for (int mt = 0; mt < 4; ++mt) {
#pragma unroll
            for (int j = 0; j < 4; ++j) {
                float m = fmaxf(fmaxf(s[mt][0][j], s[mt][1][j]), fmaxf(s[mt][2][j], s[mt][3][j]));
                m = fmaxf(m, __shfl_xor(m, 1));
                m = fmaxf(m, __shfl_xor(m, 2));
                m = fmaxf(m, __shfl_xor(m, 4));
                m = fmaxf(m, __shfl_xor(m, 8));
                float sum = 0.f;
#pragma unroll
                for (int nt = 0; nt < 4; ++nt) {
                    float e = __expf(s[mt][nt][j] - m);
                    s[mt][nt][j] = e;
                    sum += e;
                }
                sum += __shfl_xor(sum, 1);
                sum += __shfl_xor(sum, 2);
                sum += __shfl_xor(sum, 4);
                sum += __shfl_xor(sum, 8);
                float inv = 1.0f / sum;
#pragma unroll
                for (int nt = 0; nt < 4; ++nt) s[mt][nt][j] *= inv;
            }
        }
    }
    __syncthreads();   // all S-phase LDS reads done; pA may overwrite qA/kB

    // ---- write P bf16 A-frags: pA[h][mt][ks][lane][8] at smem + h*8192B
    unsigned short* pAh = (unsigned short*)smem + h * 4096;
    {
        int cb = l & 15;
#pragma unroll
        for (int mt = 0; mt < 4; ++mt)
#pragma unroll
            for (int nt = 0; nt < 4; ++nt)
#pragma unroll
                for (int j = 0; j < 4; ++j) {
                    int r = 16 * mt + (l >> 4) * 4 + j;
                    int c = 16 * nt + cb;
                    pAh[((mt * 2 + (c >> 5)) * 64 + ((r & 15) + 16 * ((c >> 3) & 3))) * 8 + (c & 7)] = f2bf(s[mt][nt][j]);
                }
    }
    __syncthreads();

    // ---- Phase 5: O = P @ V  (64x32 per head)
    f32x4 o[4][2];
    {
        bf16x8 vf[2][2];
#pragma unroll
        for (int ks = 0; ks < 2; ++ks)
#pragma unroll
            for (int ntv = 0; ntv < 2; ++ntv)
                vf[ks][ntv] = ld_frag(R2 + (((h * 2 + ks) * 2 + ntv) * 64 + l) * 8);
#pragma unroll
        for (int mt = 0; mt < 4; ++mt) {
#pragma unroll
            for (int ntv = 0; ntv < 2; ++ntv) o[mt][ntv] = z;
#pragma unroll
            for (int ks = 0; ks < 2; ++ks) {
                bf16x8 pf = ld_frag(pAh + ((mt * 2 + ks) * 64 + l) * 8);
#pragma unroll
                for (int ntv = 0; ntv < 2; ++ntv)
                    o[mt][ntv] = __builtin_amdgcn_mfma_f32_16x16x32_bf16(pf, vf[ks][ntv], o[mt][ntv], 0, 0, 0);
            }
        }
    }
    __syncthreads();   // vB reads done; xO may overwrite R2

    // ---- write xO bf16 A-frags: xO[kt=h][mt][lane][8] in R2
    {
        int cb = l & 15;
#pragma unroll
        for (int mt = 0; mt < 4; ++mt)
#pragma unroll
            for (int ntv = 0; ntv < 2; ++ntv)
#pragma unroll
                for (int j = 0; j < 4; ++j) {
                    int r = 16 * mt + (l >> 4) * 4 + j;
                    int d = 16 * ntv + cb;
                    R2[((h * 4 + mt) * 64 + ((r & 15) + 16 * (d >> 3))) * 8 + (d & 7)] = f2bf(o[mt][ntv][j]);
                }
    }
    __syncthreads();

    // ---- Phase 6: out = xO @ proj_w + proj_b. wave w owns n-tiles {2w, 2w+1}
    float* ob = out + (size_t)b * 12288;
#pragma unroll
    for (int ntl = 0; ntl < 2; ++ntl) {
        int nt = 2 * w + ntl;
        f32x4 po[4];
#pragma unroll
        for (int mt = 0; mt < 4; ++mt) po[mt] = z;
#pragma unroll
        for (int kt = 0; kt < 6; ++kt) {
            bf16x8 wf = ld_frag(wsP + ((kt * 12 + nt) * 64 + l) * 8);
#pragma unroll
            for (int mt = 0; mt < 4; ++mt) {
                bf16x8 xf = ld_frag(R2 + ((kt * 4 + mt) * 64 + l) * 8);
                po[mt] = __builtin_amdgcn_mfma_f32_16x16x32_bf16(xf, wf, po[mt], 0, 0, 0);
            }
        }
        int c = 16 * nt + (l & 15);
        float pb = proj_b[c];
#pragma unroll
        for (int mt = 0; mt < 4; ++mt)
#pragma unroll
            for (int j = 0; j < 4; ++j) {
                int r = 16 * mt + (l >> 4) * 4 + j;
                ob[r * 192 + c] = po[mt][j] + pb;
            }
    }
}

extern "C" void kernel_launch(void* const* d_in, const int* in_sizes, int n_in,
                              void* d_out, int out_size, void* d_ws, size_t ws_size,
                              hipStream_t stream) {
    const float* hidden     = (const float*)d_in[0];
    const float* mask       = (const float*)d_in[1];
    const float* qkv_w      = (const float*)d_in[2];
    const float* qkv_b      = (const float*)d_in[3];
    const float* proj_w     = (const float*)d_in[4];
    const float* proj_b     = (const float*)d_in[5];
    const float* bias_table = (const float*)d_in[6];

    unsigned short* wsQ = (unsigned short*)d_ws;          // 110592 bf16
    unsigned short* wsP = wsQ + 110592;                   // 36864 bf16

    prep_weights<<<576, 256, 0, stream>>>(qkv_w, proj_w, wsQ, wsP);
    win_attn<<<8192, 384, 0, stream>>>(hidden, mask, qkv_b, proj_b, bias_table,
                                       wsQ, wsP, (float*)d_out);
}